// Round 8
// baseline (303.487 us; speedup 1.0000x reference)
//
#include <hip/hip_runtime.h>

#define BB 2
#define NPTS 100
#define PP 1024
#define NN 1125
#define NPAD 1152
#define NSCALE 4
#define NG 16
#define KPAD 5
#define CAMTHR 0.2f

#define R 25                              // rows per i-chunk
#define IC 45                             // i-chunks (IC*R == NN)
#define JT 5                              // j-tiles of 256
#define NBLOCKS (IC * BB * JT)            // 450 blocks (co-resident: >=2/CU guaranteed)
#define NWAVES (NBLOCKS * 4)              // 1800 waves

#define TJ (NPAD * 16)                    // transposed per-(c,b) pitch: j*16+g
#define CSTRIDE_T (BB * TJ)
#define PSZ_T (IC * CSTRIDE_T)
#define PSTRIDE_O (BB * NG * NPAD)        // c-stride, old layout (P2, read by post)

#define N_ROWSUM (3 * BB * NN)            // 6750
#define N_INITV (BB * NG)                 // 32

// workspace layout (floats)
// Barrier slots: 4 slots x 1024 words (4 KB each, zeroed by memset every launch).
// Slot internals: arrival[blk] at word[blk] (private per block),
//                 done[blk] at word[512+blk] (private per block).
#define WS_BARS 0                             // 4096 floats = 16 KB
#define WS_ROWSUM 8192                        // [3][BB][NPAD] kk=0->blk8,1->blk9,2->blk10
#define WS_VS (WS_ROWSUM + 3 * BB * NPAD)     // [4][BB][NG][NPAD]  V1..V3 materialized
#define WS_P0 (WS_VS + 4 * BB * NG * NPAD)    // stage-10 partials, transposed
#define WS_P1 (WS_P0 + PSZ_T)                 // stage-9 partials, transposed
#define WS_P2 (WS_P1 + PSZ_T)                 // stage-8 partials, OLD layout (for post)

__device__ __forceinline__ float wave_sum(float s) {
#pragma unroll
    for (int m = 32; m > 0; m >>= 1) s += __shfl_xor(s, m, 64);
    return s;
}

// Grid barrier with NO shared-line polling:
//   - every block store-releases a PRIVATE arrival word (parallel, fire-and-forget)
//   - block 0's threads each acquire-poll ~2 distinct arrival words (1 poller/word)
//   - block 0 then store-releases PRIVATE done words
//   - each waiter acquire-polls only its OWN done word (<=16 pollers/line, slow rate)
__device__ __forceinline__ void grid_bar(float* wsf, int slot) {
    unsigned* base = (unsigned*)wsf + slot * 1024;
    unsigned* arr = base;                 // words [0..NBLOCKS)
    unsigned* done = base + 512;          // words [512..512+NBLOCKS)
    __syncthreads();                      // drains each wave's stores (vmcnt0 @ s_barrier)
    if (blockIdx.x == 0) {
        if (threadIdx.x == 0)
            __hip_atomic_store(arr, 1u, __ATOMIC_RELEASE, __HIP_MEMORY_SCOPE_AGENT);
        for (int w = threadIdx.x; w < NBLOCKS; w += 256) {
            while (__hip_atomic_load(arr + w, __ATOMIC_ACQUIRE,
                                     __HIP_MEMORY_SCOPE_AGENT) == 0)
                __builtin_amdgcn_s_sleep(4);
        }
        __syncthreads();                  // all arrivals observed by the whole block
        for (int w = threadIdx.x; w < NBLOCKS; w += 256)
            __hip_atomic_store(done + w, 1u, __ATOMIC_RELEASE,
                               __HIP_MEMORY_SCOPE_AGENT);
        __syncthreads();
    } else {
        if (threadIdx.x == 0) {
            __hip_atomic_store(arr + blockIdx.x, 1u, __ATOMIC_RELEASE,
                               __HIP_MEMORY_SCOPE_AGENT);
            while (__hip_atomic_load(done + blockIdx.x, __ATOMIC_ACQUIRE,
                                     __HIP_MEMORY_SCOPE_AGENT) == 0)
                __builtin_amdgcn_s_sleep(16);
        }
        __syncthreads();
    }
}

// One stage phase (proven r5/r7). Block (ic,b,jt):
//   W-window from materialized vin (stage 10) or fused coalesced reduce of prevP
//   (transposed [c][b][j*16+g]); jt==0 blocks materialize V_in for post.
//   Multiply window against A rows + diagonal identity; write transposed (outT=1)
//   or old layout (outT=0, consumed by post).
__device__ __forceinline__ void stage_phase(const float* __restrict__ A,
                                            float* __restrict__ ws, float* Wl,
                                            const float* __restrict__ rsb,
                                            const float* __restrict__ vin,
                                            const float* __restrict__ prevP,
                                            float* __restrict__ curP,
                                            float* __restrict__ vout,
                                            int blk, int outT) {
    int x = blockIdx.x;
    int jt = x % JT;
    int b = (x / JT) % BB;
    int ic = x / (JT * BB);
    int i0 = ic * R;
    const float* rs = rsb + b * NPAD;
    if (prevP) {
        for (int idx = threadIdx.x; idx < R * NG; idx += 256) {
            const float* pp = prevP + (size_t)b * TJ + i0 * 16 + idx;
            float s = 0.f;
#pragma unroll
            for (int c = 0; c < IC; ++c) s += pp[(size_t)c * CSTRIDE_T];
            int il = idx >> 4, g = idx & 15;
            if (jt == 0)
                vout[((size_t)(b * NG) + g) * NPAD + i0 + il] = s;
            Wl[idx] = s / rs[i0 + il];
        }
    } else {
        for (int idx = threadIdx.x; idx < R * NG; idx += 256) {
            int il = idx >> 4, g = idx & 15;
            Wl[idx] = vin[((size_t)(b * NG) + g) * NPAD + i0 + il] / rs[i0 + il];
        }
    }
    __syncthreads();
    int j = jt * 256 + threadIdx.x;
    if (j < NN) {
        float acc[NG];
#pragma unroll
        for (int g = 0; g < NG; ++g) acc[g] = 0.f;
        const float* Ab = A + (((size_t)blk * BB + b) * NN + i0) * NN + j;
#pragma unroll
        for (int il = 0; il < R; ++il) {
            float a = Ab[(size_t)il * NN];
#pragma unroll
            for (int g = 0; g < NG; ++g) acc[g] += Wl[il * NG + g] * a;
        }
        int d = j - i0;
        if (d >= 0 && d < R) {            // identity term: diagonal chunk only
#pragma unroll
            for (int g = 0; g < NG; ++g) acc[g] += Wl[d * NG + g];
        }
        if (outT) {
            float* po = curP + (size_t)(ic * BB + b) * TJ + (size_t)j * 16;
#pragma unroll
            for (int g = 0; g < NG; g += 4)
                *(float4*)(po + g) = make_float4(acc[g], acc[g + 1], acc[g + 2], acc[g + 3]);
        } else {
            float* po = curP + (size_t)(ic * BB + b) * NG * NPAD + j;
#pragma unroll
            for (int g = 0; g < NG; ++g) po[(size_t)g * NPAD] = acc[g];
        }
    }
}

// ---------------------------------------------------------------------------
// Single fused kernel: prep | S10 | S9 | S8 | post, with 4 private-word barriers.
__global__ __launch_bounds__(256, 2) void mega_kernel(const float* __restrict__ A,
                                                      const int* __restrict__ pos,
                                                      float* __restrict__ ws,
                                                      float* __restrict__ out) {
    __shared__ float Wl[R * NG];
    __shared__ float img[1024];
    __shared__ float tmp[1024];
    __shared__ float redA[256];
    __shared__ float redB[256];
    int wave = threadIdx.x >> 6, lane = threadIdx.x & 63;
    int gwave = blockIdx.x * 4 + wave;

    // Phase 0: rowsums (+1) of blocks 8..10; initial vectors V3 from norm aug[11].
    for (int task = gwave; task < N_ROWSUM + N_INITV; task += NWAVES) {
        if (task < N_ROWSUM) {
            int i = task % NN;
            int b = (task / NN) % BB;
            int kk = task / (NN * BB);
            const float* row = A + (((size_t)(8 + kk) * BB + b) * NN + i) * NN;
            float s = 0.f;
#pragma unroll
            for (int k = 0; k < 17; ++k) s += row[lane + 64 * k];
            if (lane < NN - 17 * 64) s += row[lane + 17 * 64];
            s = wave_sum(s);
            if (lane == 0) ws[WS_ROWSUM + (kk * BB + b) * NPAD + i] = s + 1.0f;
        } else {
            int t = task - N_ROWSUM;
            int g = t % NG, b = t / NG;
            int r = NN - NPTS + pos[b * NG + g];
            const float* row = A + (((size_t)11 * BB + b) * NN + r) * NN;
            float s = 0.f;
#pragma unroll
            for (int k = 0; k < 17; ++k) s += row[lane + 64 * k];
            if (lane < NN - 17 * 64) s += row[lane + 17 * 64];
            s = wave_sum(s);
            float inv = 1.0f / (s + 1.0f);
            float* v = ws + WS_VS + ((size_t)(3 * BB + b) * NG + g) * NPAD;
            for (int j = lane; j < NN; j += 64)
                v[j] = (row[j] + (j == r ? 1.0f : 0.0f)) * inv;
        }
    }
    grid_bar(ws, 0);
    // S10: V3 -> P0 (transposed)
    stage_phase(A, ws, Wl, ws + WS_ROWSUM + 2 * BB * NPAD,
                ws + WS_VS + (size_t)3 * BB * NG * NPAD, nullptr,
                ws + WS_P0, nullptr, 10, 1);
    grid_bar(ws, 1);
    // S9: fused reduce(P0) -> V2 (jt==0) ; multiply -> P1 (transposed)
    stage_phase(A, ws, Wl, ws + WS_ROWSUM + 1 * BB * NPAD,
                nullptr, ws + WS_P0,
                ws + WS_P1, ws + WS_VS + (size_t)2 * BB * NG * NPAD, 9, 1);
    grid_bar(ws, 2);
    // S8: fused reduce(P1) -> V1 (jt==0) ; multiply -> P2 (old layout)
    stage_phase(A, ws, Wl, ws + WS_ROWSUM + 0 * BB * NPAD,
                nullptr, ws + WS_P1,
                ws + WS_P2, ws + WS_VS + (size_t)1 * BB * NG * NPAD, 8, 0);
    grid_bar(ws, 3);

    // Phase post: blocks 0..127, 4 pixels/thread. Same FP order as proven kernel.
    int idx = blockIdx.x;
    if (idx >= BB * NG * NSCALE) return;
    int s = idx % NSCALE;
    int g = (idx / NSCALE) % NG;
    int b = idx / (NSCALE * NG);
    int tid = threadIdx.x;
    float cam[4];
#pragma unroll
    for (int k = 0; k < 4; ++k) {
        int p = tid + 256 * k;
        if (s == 0) {                      // fused reduce of stage-8 partials
            const float* pp = ws + WS_P2 + (size_t)(b * NG + g) * NPAD + 1 + p;
            float t = 0.f;
#pragma unroll
            for (int c = 0; c < IC; ++c) t += pp[(size_t)c * PSTRIDE_O];
            cam[k] = t;
        } else {
            cam[k] = ws[WS_VS + ((size_t)(s * BB + b) * NG + g) * NPAD + 1 + p];
        }
    }
    redA[tid] = fminf(fminf(cam[0], cam[1]), fminf(cam[2], cam[3]));
    redB[tid] = fmaxf(fmaxf(cam[0], cam[1]), fmaxf(cam[2], cam[3]));
    __syncthreads();
    for (int st = 128; st > 0; st >>= 1) {
        if (tid < st) {
            redA[tid] = fminf(redA[tid], redA[tid + st]);
            redB[tid] = fmaxf(redB[tid], redB[tid + st]);
        }
        __syncthreads();
    }
    float mn = redA[0], mx = redB[0];
#pragma unroll
    for (int k = 0; k < 4; ++k) {
        int p = tid + 256 * k;
        float camn = (cam[k] - mn) / (mx - mn + 1e-6f);
        out[(size_t)idx * PP + p] = camn;
        img[p] = camn >= CAMTHR ? 1.0f : 0.0f;
    }
    __syncthreads();
    // dilate horizontal (pad-0 under max == clip), img -> tmp
#pragma unroll
    for (int k = 0; k < 4; ++k) {
        int p = tid + 256 * k, y = p >> 5, x = p & 31;
        float m = 0.f;
        for (int dx = -KPAD; dx <= KPAD; ++dx) {
            int xx = x + dx;
            if (xx >= 0 && xx < 32) m = fmaxf(m, img[(y << 5) | xx]);
        }
        tmp[p] = m;
    }
    __syncthreads();
    // dilate vertical, tmp -> img
#pragma unroll
    for (int k = 0; k < 4; ++k) {
        int p = tid + 256 * k, y = p >> 5, x = p & 31;
        float m = 0.f;
        for (int dy = -KPAD; dy <= KPAD; ++dy) {
            int yy = y + dy;
            if (yy >= 0 && yy < 32) m = fmaxf(m, tmp[(yy << 5) | x]);
        }
        img[p] = m;
    }
    __syncthreads();
    // erode horizontal (zero-pad: border forced 0), img -> tmp
#pragma unroll
    for (int k = 0; k < 4; ++k) {
        int p = tid + 256 * k, y = p >> 5, x = p & 31;
        float e;
        if (x < KPAD || x > 31 - KPAD) {
            e = 0.f;
        } else {
            e = 1e30f;
            for (int dx = -KPAD; dx <= KPAD; ++dx) e = fminf(e, img[(y << 5) | (x + dx)]);
        }
        tmp[p] = e;
    }
    __syncthreads();
    // erode vertical -> closed output + fg, accumulate bbox extents
    float xmn = 1e9f, xmx = -1e9f, ymn = 1e9f, ymx = -1e9f;
#pragma unroll
    for (int k = 0; k < 4; ++k) {
        int p = tid + 256 * k, y = p >> 5, x = p & 31;
        float ev;
        if (y < KPAD || y > 31 - KPAD) {
            ev = 0.f;
        } else {
            ev = 1e30f;
            for (int dy = -KPAD; dy <= KPAD; ++dy) ev = fminf(ev, tmp[((y + dy) << 5) | x]);
        }
        out[(size_t)(BB * NG * NSCALE) * PP + (size_t)idx * PP + p] = ev;
        bool fg = ev > 0.5f;
        xmn = fminf(xmn, fg ? (float)x : 1e9f);
        xmx = fmaxf(xmx, fg ? (float)x : -1e9f);
        ymn = fminf(ymn, fg ? (float)y : 1e9f);
        ymx = fmaxf(ymx, fg ? (float)y : -1e9f);
    }
    __syncthreads();
    redA[tid] = xmn;
    redB[tid] = xmx;
    __syncthreads();
    for (int st = 128; st > 0; st >>= 1) {
        if (tid < st) {
            redA[tid] = fminf(redA[tid], redA[tid + st]);
            redB[tid] = fmaxf(redB[tid], redB[tid + st]);
        }
        __syncthreads();
    }
    float xmin = redA[0], xmax = redB[0];
    __syncthreads();
    redA[tid] = ymn;
    redB[tid] = ymx;
    __syncthreads();
    for (int st = 128; st > 0; st >>= 1) {
        if (tid < st) {
            redA[tid] = fminf(redA[tid], redA[tid + st]);
            redB[tid] = fmaxf(redB[tid], redB[tid + st]);
        }
        __syncthreads();
    }
    if (tid == 0) {
        float ymin = redA[0], ymax = redB[0];
        float* bb = out + (size_t)(BB * NG * NSCALE) * PP * 2 + (size_t)idx * 4;
        if (xmax < -1e8f) {
            bb[0] = 0.f; bb[1] = 0.f; bb[2] = 1.f; bb[3] = 1.f;
        } else {
            bb[0] = xmin; bb[1] = ymin; bb[2] = xmax; bb[3] = ymax;
        }
    }
}

extern "C" void kernel_launch(void* const* d_in, const int* in_sizes, int n_in,
                              void* d_out, int out_size, void* d_ws, size_t ws_size,
                              hipStream_t stream) {
    const float* A = (const float*)d_in[0];
    const int* pos = (const int*)d_in[1];
    float* out = (float*)d_out;
    float* ws = (float*)d_ws;

    // zero the 4 barrier slots (4 x 4 KB), deterministic across graph replays
    hipMemsetAsync(ws, 0, 4 * 4096, stream);
    mega_kernel<<<NBLOCKS, 256, 0, stream>>>(A, pos, ws, out);
}

// Round 9
// 122.522 us; speedup vs baseline: 2.4770x; 2.4770x over previous
//
#include <hip/hip_runtime.h>

#define BB 2
#define NPTS 100
#define PP 1024
#define NN 1125
#define NPAD 1152
#define NSCALE 4
#define NG 16
#define KPAD 5
#define CAMTHR 0.2f

#define R 25                              // rows per i-chunk
#define IC 45                             // i-chunks (IC*R == NN)
#define JT 5                              // j-tiles of 256
#define NBLOCKS (IC * BB * JT)            // 450 blocks (co-resident: >=2/CU guaranteed)
#define NWAVES (NBLOCKS * 4)              // 1800 waves

#define TJ (NPAD * 16)                    // transposed per-(c,b) pitch: j*16+g
#define CSTRIDE_T (BB * TJ)
#define PSZ_T (IC * CSTRIDE_T)
#define PSTRIDE_O (BB * NG * NPAD)        // c-stride, old layout (P2, read by post)

#define N_ROWSUM (3 * BB * NN)            // 6750
#define N_INITV (BB * NG)                 // 32

// workspace layout (floats)
// Barrier slots: 4 slots x 1024 words (4 KB each, zeroed by memset every launch).
// Slot internals: arrival[blk] at word[blk], done[blk] at word[512+blk].
#define WS_BARS 0                             // 4096 floats = 16 KB
#define WS_ROWSUM 8192                        // [3][BB][NPAD] kk=0->blk8,1->blk9,2->blk10
#define WS_VS (WS_ROWSUM + 3 * BB * NPAD)     // [4][BB][NG][NPAD]  V1..V3 materialized
#define WS_P0 (WS_VS + 4 * BB * NG * NPAD)    // stage-10 partials, transposed
#define WS_P1 (WS_P0 + PSZ_T)                 // stage-9 partials, transposed
#define WS_P2 (WS_P1 + PSZ_T)                 // stage-8 partials, OLD layout (for post)

__device__ __forceinline__ float wave_sum(float s) {
#pragma unroll
    for (int m = 32; m > 0; m >>= 1) s += __shfl_xor(s, m, 64);
    return s;
}

// Spin-read via atomic RMW: executes at the coherence point (LLC), can never be
// served from a stale per-XCD L2 line (acquire LOADS can -> ~60us eviction waits,
// the r4/r7/r8 failure mode).
__device__ __forceinline__ unsigned poll_rmw(unsigned* p) {
    return __hip_atomic_fetch_add(p, 0u, __ATOMIC_RELAXED, __HIP_MEMORY_SCOPE_AGENT);
}

// Grid barrier: private arrival/done words, RMW-based polling, explicit fences.
__device__ __forceinline__ void grid_bar(float* wsf, int slot) {
    unsigned* base = (unsigned*)wsf + slot * 1024;
    unsigned* arr = base;                 // words [0..NBLOCKS)
    unsigned* done = base + 512;          // words [512..512+NBLOCKS)
    __syncthreads();                      // drains this block's stores
    if (blockIdx.x == 0) {
        if (threadIdx.x == 0) {
            __builtin_amdgcn_fence(__ATOMIC_RELEASE, "agent");
            __hip_atomic_store(arr, 1u, __ATOMIC_RELAXED, __HIP_MEMORY_SCOPE_AGENT);
        }
        for (int w = threadIdx.x; w < NBLOCKS; w += 256) {
            while (poll_rmw(arr + w) == 0) __builtin_amdgcn_s_sleep(2);
        }
        __builtin_amdgcn_fence(__ATOMIC_ACQUIRE, "agent");
        __syncthreads();                  // all arrivals observed by whole block
        __builtin_amdgcn_fence(__ATOMIC_RELEASE, "agent");
        for (int w = threadIdx.x; w < NBLOCKS; w += 256)
            __hip_atomic_store(done + w, 1u, __ATOMIC_RELAXED,
                               __HIP_MEMORY_SCOPE_AGENT);
        __syncthreads();
    } else {
        if (threadIdx.x == 0) {
            __builtin_amdgcn_fence(__ATOMIC_RELEASE, "agent");
            __hip_atomic_store(arr + blockIdx.x, 1u, __ATOMIC_RELAXED,
                               __HIP_MEMORY_SCOPE_AGENT);
            while (poll_rmw(done + blockIdx.x) == 0) __builtin_amdgcn_s_sleep(8);
            __builtin_amdgcn_fence(__ATOMIC_ACQUIRE, "agent");
        }
        __syncthreads();
    }
}

// One stage phase (proven r5/r7/r8). Block (ic,b,jt):
//   W-window from materialized vin (stage 10) or fused coalesced reduce of prevP
//   (transposed [c][b][j*16+g]); jt==0 blocks materialize V_in for post.
//   Multiply window against A rows + diagonal identity; write transposed (outT=1)
//   or old layout (outT=0, consumed by post).
__device__ __forceinline__ void stage_phase(const float* __restrict__ A,
                                            float* __restrict__ ws, float* Wl,
                                            const float* __restrict__ rsb,
                                            const float* __restrict__ vin,
                                            const float* __restrict__ prevP,
                                            float* __restrict__ curP,
                                            float* __restrict__ vout,
                                            int blk, int outT) {
    int x = blockIdx.x;
    int jt = x % JT;
    int b = (x / JT) % BB;
    int ic = x / (JT * BB);
    int i0 = ic * R;
    const float* rs = rsb + b * NPAD;
    if (prevP) {
        for (int idx = threadIdx.x; idx < R * NG; idx += 256) {
            const float* pp = prevP + (size_t)b * TJ + i0 * 16 + idx;
            float s = 0.f;
#pragma unroll
            for (int c = 0; c < IC; ++c) s += pp[(size_t)c * CSTRIDE_T];
            int il = idx >> 4, g = idx & 15;
            if (jt == 0)
                vout[((size_t)(b * NG) + g) * NPAD + i0 + il] = s;
            Wl[idx] = s / rs[i0 + il];
        }
    } else {
        for (int idx = threadIdx.x; idx < R * NG; idx += 256) {
            int il = idx >> 4, g = idx & 15;
            Wl[idx] = vin[((size_t)(b * NG) + g) * NPAD + i0 + il] / rs[i0 + il];
        }
    }
    __syncthreads();
    int j = jt * 256 + threadIdx.x;
    if (j < NN) {
        float acc[NG];
#pragma unroll
        for (int g = 0; g < NG; ++g) acc[g] = 0.f;
        const float* Ab = A + (((size_t)blk * BB + b) * NN + i0) * NN + j;
#pragma unroll
        for (int il = 0; il < R; ++il) {
            float a = Ab[(size_t)il * NN];
#pragma unroll
            for (int g = 0; g < NG; ++g) acc[g] += Wl[il * NG + g] * a;
        }
        int d = j - i0;
        if (d >= 0 && d < R) {            // identity term: diagonal chunk only
#pragma unroll
            for (int g = 0; g < NG; ++g) acc[g] += Wl[d * NG + g];
        }
        if (outT) {
            float* po = curP + (size_t)(ic * BB + b) * TJ + (size_t)j * 16;
#pragma unroll
            for (int g = 0; g < NG; g += 4)
                *(float4*)(po + g) = make_float4(acc[g], acc[g + 1], acc[g + 2], acc[g + 3]);
        } else {
            float* po = curP + (size_t)(ic * BB + b) * NG * NPAD + j;
#pragma unroll
            for (int g = 0; g < NG; ++g) po[(size_t)g * NPAD] = acc[g];
        }
    }
}

// ---------------------------------------------------------------------------
// Single fused kernel: prep | S10 | S9 | S8 | post, with 4 RMW-poll barriers.
__global__ __launch_bounds__(256, 2) void mega_kernel(const float* __restrict__ A,
                                                      const int* __restrict__ pos,
                                                      float* __restrict__ ws,
                                                      float* __restrict__ out) {
    __shared__ float Wl[R * NG];
    __shared__ float img[1024];
    __shared__ float tmp[1024];
    __shared__ float redA[256];
    __shared__ float redB[256];
    int wave = threadIdx.x >> 6, lane = threadIdx.x & 63;
    int gwave = blockIdx.x * 4 + wave;

    // Phase 0: rowsums (+1) of blocks 8..10; initial vectors V3 from norm aug[11].
    for (int task = gwave; task < N_ROWSUM + N_INITV; task += NWAVES) {
        if (task < N_ROWSUM) {
            int i = task % NN;
            int b = (task / NN) % BB;
            int kk = task / (NN * BB);
            const float* row = A + (((size_t)(8 + kk) * BB + b) * NN + i) * NN;
            float s = 0.f;
#pragma unroll
            for (int k = 0; k < 17; ++k) s += row[lane + 64 * k];
            if (lane < NN - 17 * 64) s += row[lane + 17 * 64];
            s = wave_sum(s);
            if (lane == 0) ws[WS_ROWSUM + (kk * BB + b) * NPAD + i] = s + 1.0f;
        } else {
            int t = task - N_ROWSUM;
            int g = t % NG, b = t / NG;
            int r = NN - NPTS + pos[b * NG + g];
            const float* row = A + (((size_t)11 * BB + b) * NN + r) * NN;
            float s = 0.f;
#pragma unroll
            for (int k = 0; k < 17; ++k) s += row[lane + 64 * k];
            if (lane < NN - 17 * 64) s += row[lane + 17 * 64];
            s = wave_sum(s);
            float inv = 1.0f / (s + 1.0f);
            float* v = ws + WS_VS + ((size_t)(3 * BB + b) * NG + g) * NPAD;
            for (int j = lane; j < NN; j += 64)
                v[j] = (row[j] + (j == r ? 1.0f : 0.0f)) * inv;
        }
    }
    grid_bar(ws, 0);
    // S10: V3 -> P0 (transposed)
    stage_phase(A, ws, Wl, ws + WS_ROWSUM + 2 * BB * NPAD,
                ws + WS_VS + (size_t)3 * BB * NG * NPAD, nullptr,
                ws + WS_P0, nullptr, 10, 1);
    grid_bar(ws, 1);
    // S9: fused reduce(P0) -> V2 (jt==0) ; multiply -> P1 (transposed)
    stage_phase(A, ws, Wl, ws + WS_ROWSUM + 1 * BB * NPAD,
                nullptr, ws + WS_P0,
                ws + WS_P1, ws + WS_VS + (size_t)2 * BB * NG * NPAD, 9, 1);
    grid_bar(ws, 2);
    // S8: fused reduce(P1) -> V1 (jt==0) ; multiply -> P2 (old layout)
    stage_phase(A, ws, Wl, ws + WS_ROWSUM + 0 * BB * NPAD,
                nullptr, ws + WS_P1,
                ws + WS_P2, ws + WS_VS + (size_t)1 * BB * NG * NPAD, 8, 0);
    grid_bar(ws, 3);

    // Phase post: blocks 0..127, 4 pixels/thread. Same FP order as proven kernel.
    int idx = blockIdx.x;
    if (idx >= BB * NG * NSCALE) return;
    int s = idx % NSCALE;
    int g = (idx / NSCALE) % NG;
    int b = idx / (NSCALE * NG);
    int tid = threadIdx.x;
    float cam[4];
#pragma unroll
    for (int k = 0; k < 4; ++k) {
        int p = tid + 256 * k;
        if (s == 0) {                      // fused reduce of stage-8 partials
            const float* pp = ws + WS_P2 + (size_t)(b * NG + g) * NPAD + 1 + p;
            float t = 0.f;
#pragma unroll
            for (int c = 0; c < IC; ++c) t += pp[(size_t)c * PSTRIDE_O];
            cam[k] = t;
        } else {
            cam[k] = ws[WS_VS + ((size_t)(s * BB + b) * NG + g) * NPAD + 1 + p];
        }
    }
    redA[tid] = fminf(fminf(cam[0], cam[1]), fminf(cam[2], cam[3]));
    redB[tid] = fmaxf(fmaxf(cam[0], cam[1]), fmaxf(cam[2], cam[3]));
    __syncthreads();
    for (int st = 128; st > 0; st >>= 1) {
        if (tid < st) {
            redA[tid] = fminf(redA[tid], redA[tid + st]);
            redB[tid] = fmaxf(redB[tid], redB[tid + st]);
        }
        __syncthreads();
    }
    float mn = redA[0], mx = redB[0];
#pragma unroll
    for (int k = 0; k < 4; ++k) {
        int p = tid + 256 * k;
        float camn = (cam[k] - mn) / (mx - mn + 1e-6f);
        out[(size_t)idx * PP + p] = camn;
        img[p] = camn >= CAMTHR ? 1.0f : 0.0f;
    }
    __syncthreads();
    // dilate horizontal (pad-0 under max == clip), img -> tmp
#pragma unroll
    for (int k = 0; k < 4; ++k) {
        int p = tid + 256 * k, y = p >> 5, x = p & 31;
        float m = 0.f;
        for (int dx = -KPAD; dx <= KPAD; ++dx) {
            int xx = x + dx;
            if (xx >= 0 && xx < 32) m = fmaxf(m, img[(y << 5) | xx]);
        }
        tmp[p] = m;
    }
    __syncthreads();
    // dilate vertical, tmp -> img
#pragma unroll
    for (int k = 0; k < 4; ++k) {
        int p = tid + 256 * k, y = p >> 5, x = p & 31;
        float m = 0.f;
        for (int dy = -KPAD; dy <= KPAD; ++dy) {
            int yy = y + dy;
            if (yy >= 0 && yy < 32) m = fmaxf(m, tmp[(yy << 5) | x]);
        }
        img[p] = m;
    }
    __syncthreads();
    // erode horizontal (zero-pad: border forced 0), img -> tmp
#pragma unroll
    for (int k = 0; k < 4; ++k) {
        int p = tid + 256 * k, y = p >> 5, x = p & 31;
        float e;
        if (x < KPAD || x > 31 - KPAD) {
            e = 0.f;
        } else {
            e = 1e30f;
            for (int dx = -KPAD; dx <= KPAD; ++dx) e = fminf(e, img[(y << 5) | (x + dx)]);
        }
        tmp[p] = e;
    }
    __syncthreads();
    // erode vertical -> closed output + fg, accumulate bbox extents
    float xmn = 1e9f, xmx = -1e9f, ymn = 1e9f, ymx = -1e9f;
#pragma unroll
    for (int k = 0; k < 4; ++k) {
        int p = tid + 256 * k, y = p >> 5, x = p & 31;
        float ev;
        if (y < KPAD || y > 31 - KPAD) {
            ev = 0.f;
        } else {
            ev = 1e30f;
            for (int dy = -KPAD; dy <= KPAD; ++dy) ev = fminf(ev, tmp[((y + dy) << 5) | x]);
        }
        out[(size_t)(BB * NG * NSCALE) * PP + (size_t)idx * PP + p] = ev;
        bool fg = ev > 0.5f;
        xmn = fminf(xmn, fg ? (float)x : 1e9f);
        xmx = fmaxf(xmx, fg ? (float)x : -1e9f);
        ymn = fminf(ymn, fg ? (float)y : 1e9f);
        ymx = fmaxf(ymx, fg ? (float)y : -1e9f);
    }
    __syncthreads();
    redA[tid] = xmn;
    redB[tid] = xmx;
    __syncthreads();
    for (int st = 128; st > 0; st >>= 1) {
        if (tid < st) {
            redA[tid] = fminf(redA[tid], redA[tid + st]);
            redB[tid] = fmaxf(redB[tid], redB[tid + st]);
        }
        __syncthreads();
    }
    float xmin = redA[0], xmax = redB[0];
    __syncthreads();
    redA[tid] = ymn;
    redB[tid] = ymx;
    __syncthreads();
    for (int st = 128; st > 0; st >>= 1) {
        if (tid < st) {
            redA[tid] = fminf(redA[tid], redA[tid + st]);
            redB[tid] = fmaxf(redB[tid], redB[tid + st]);
        }
        __syncthreads();
    }
    if (tid == 0) {
        float ymin = redA[0], ymax = redB[0];
        float* bb = out + (size_t)(BB * NG * NSCALE) * PP * 2 + (size_t)idx * 4;
        if (xmax < -1e8f) {
            bb[0] = 0.f; bb[1] = 0.f; bb[2] = 1.f; bb[3] = 1.f;
        } else {
            bb[0] = xmin; bb[1] = ymin; bb[2] = xmax; bb[3] = ymax;
        }
    }
}

extern "C" void kernel_launch(void* const* d_in, const int* in_sizes, int n_in,
                              void* d_out, int out_size, void* d_ws, size_t ws_size,
                              hipStream_t stream) {
    const float* A = (const float*)d_in[0];
    const int* pos = (const int*)d_in[1];
    float* out = (float*)d_out;
    float* ws = (float*)d_ws;

    // zero the 4 barrier slots (4 x 4 KB), deterministic across graph replays
    hipMemsetAsync(ws, 0, 4 * 4096, stream);
    mega_kernel<<<NBLOCKS, 256, 0, stream>>>(A, pos, ws, out);
}

// Round 10
// 53.179 us; speedup vs baseline: 5.7069x; 2.3039x over previous
//
#include <hip/hip_runtime.h>

#define BB 2
#define NPTS 100
#define PP 1024
#define NN 1125
#define NPAD 1152
#define NSCALE 4
#define NG 16
#define KPAD 5
#define CAMTHR 0.2f

#define R 25                              // rows per i-chunk
#define IC 45                             // i-chunks (IC*R == NN)
#define STG_THREADS 512
#define STG_JT 3                          // ceil(NN / 512)

#define TJ (NPAD * 16)                    // transposed per-(c,b) pitch: j*16+g
#define CSTRIDE_T (BB * TJ)
#define PSZ_T (IC * CSTRIDE_T)
#define PSTRIDE_O (BB * NG * NPAD)        // c-stride, old layout (P2, read by post)

#define N_ROWSUM (3 * BB * NN)            // 6750
#define N_INITV (BB * NG)                 // 32

// workspace layout (floats)
#define WS_ROWSUM 0                           // [3][BB][NPAD] kk=0->blk8,1->blk9,2->blk10
#define WS_VS (WS_ROWSUM + 3 * BB * NPAD)     // [4][BB][NG][NPAD]  V1..V3 materialized
#define WS_P0 (WS_VS + 4 * BB * NG * NPAD)    // stage-10 partials, transposed
#define WS_P1 (WS_P0 + PSZ_T)                 // stage-9 partials, transposed
#define WS_P2 (WS_P1 + PSZ_T)                 // stage-8 partials, OLD layout (for post)

__device__ __forceinline__ float wave_sum(float s) {
#pragma unroll
    for (int m = 32; m > 0; m >>= 1) s += __shfl_xor(s, m, 64);
    return s;
}

// ---------------------------------------------------------------------------
// K1 (proven r2): wave-per-row. Tasks 0..6749: rowsums (+1) of aug blocks 8..10.
//     Tasks 6750..6781: initial vectors V3 = row r of normalized aug[11].
__global__ __launch_bounds__(256) void prep_kernel(const float* __restrict__ A,
                                                   const int* __restrict__ pos,
                                                   float* __restrict__ ws) {
    int wave = threadIdx.x >> 6;
    int lane = threadIdx.x & 63;
    int task = blockIdx.x * 4 + wave;
    if (task < N_ROWSUM) {
        int i = task % NN;
        int b = (task / NN) % BB;
        int kk = task / (NN * BB);
        const float* row = A + (((size_t)(8 + kk) * BB + b) * NN + i) * NN;
        float s = 0.f;
#pragma unroll
        for (int k = 0; k < 17; ++k) s += row[lane + 64 * k];
        if (lane < NN - 17 * 64) s += row[lane + 17 * 64];
        s = wave_sum(s);
        if (lane == 0) ws[WS_ROWSUM + (kk * BB + b) * NPAD + i] = s + 1.0f;
    } else if (task < N_ROWSUM + N_INITV) {
        int t = task - N_ROWSUM;
        int g = t % NG;
        int b = t / NG;
        int r = NN - NPTS + pos[b * NG + g];
        const float* row = A + (((size_t)11 * BB + b) * NN + r) * NN;
        float s = 0.f;
#pragma unroll
        for (int k = 0; k < 17; ++k) s += row[lane + 64 * k];
        if (lane < NN - 17 * 64) s += row[lane + 17 * 64];
        s = wave_sum(s);
        float inv = 1.0f / (s + 1.0f);
        float* v = ws + WS_VS + ((size_t)(3 * BB + b) * NG + g) * NPAD;
        for (int j = lane; j < NN; j += 64)
            v[j] = (row[j] + (j == r ? 1.0f : 0.0f)) * inv;
    }
}

// ---------------------------------------------------------------------------
// K2: one stage. Block (ic,b) OWNS its 25-row window exclusively (jt moved
// inside as a 3-iteration loop over 512-wide j-tiles):
//   W-window: from materialized vin (stage 10) or fused ONE-TIME coalesced
//   reduce of prevP (transposed [c][b][j*16+g]); reduce path also materializes
//   V_in for post — once, no redundancy, no jt guard.
//   Multiply: partial[g][j] = sum_il w*A[i0+il][j] (+ diagonal identity),
//   written transposed (outT=1) or old-layout (outT=0, consumed by post).
__global__ __launch_bounds__(STG_THREADS) void stage_kernel(
        const float* __restrict__ A, const float* __restrict__ rsb,
        const float* __restrict__ vin, const float* __restrict__ prevP,
        float* __restrict__ curP, float* __restrict__ vout, int blk, int outT) {
    __shared__ float Wl[R * NG];          // [il][g]
    int b = blockIdx.x % BB;
    int ic = blockIdx.x / BB;
    int i0 = ic * R;
    const float* rs = rsb + b * NPAD;
    if (prevP) {
        for (int idx = threadIdx.x; idx < R * NG; idx += STG_THREADS) {
            const float* pp = prevP + (size_t)b * TJ + i0 * 16 + idx;
            float s = 0.f;
#pragma unroll
            for (int c = 0; c < IC; ++c) s += pp[(size_t)c * CSTRIDE_T];
            int il = idx >> 4, g = idx & 15;
            vout[((size_t)(b * NG) + g) * NPAD + i0 + il] = s;   // unique owner
            Wl[idx] = s / rs[i0 + il];
        }
    } else {
        for (int idx = threadIdx.x; idx < R * NG; idx += STG_THREADS) {
            int il = idx >> 4, g = idx & 15;
            Wl[idx] = vin[((size_t)(b * NG) + g) * NPAD + i0 + il] / rs[i0 + il];
        }
    }
    __syncthreads();
    const float* Ab0 = A + (((size_t)blk * BB + b) * NN + i0) * NN;
#pragma unroll
    for (int jt = 0; jt < STG_JT; ++jt) {
        int j = jt * STG_THREADS + threadIdx.x;
        if (j < NN) {
            float acc[NG];
#pragma unroll
            for (int g = 0; g < NG; ++g) acc[g] = 0.f;
            const float* Ab = Ab0 + j;
#pragma unroll
            for (int il = 0; il < R; ++il) {
                float a = Ab[(size_t)il * NN];
#pragma unroll
                for (int g = 0; g < NG; ++g) acc[g] += Wl[il * NG + g] * a;
            }
            int d = j - i0;
            if (d >= 0 && d < R) {        // identity term: diagonal chunk only
#pragma unroll
                for (int g = 0; g < NG; ++g) acc[g] += Wl[d * NG + g];
            }
            if (outT) {
                float* po = curP + (size_t)(ic * BB + b) * TJ + (size_t)j * 16;
#pragma unroll
                for (int g = 0; g < NG; g += 4)
                    *(float4*)(po + g) =
                        make_float4(acc[g], acc[g + 1], acc[g + 2], acc[g + 3]);
            } else {
                float* po = curP + (size_t)(ic * BB + b) * NG * NPAD + j;
#pragma unroll
                for (int g = 0; g < NG; ++g) po[(size_t)g * NPAD] = acc[g];
            }
        }
    }
}

// ---------------------------------------------------------------------------
// K3 (proven r2/r5): per-image normalize, binarize, morph close (zero-pad), bbox.
//     s==0 images reduce V0 from the stage-8 partials (old layout, coalesced).
__global__ __launch_bounds__(1024) void post_kernel(const float* __restrict__ ws,
                                                    float* __restrict__ out) {
    __shared__ float redA[1024];
    __shared__ float redB[1024];
    __shared__ float img[1024];
    __shared__ float tmp[1024];
    int idx = blockIdx.x;                 // (b*NG+g)*NSCALE + s
    int s = idx % NSCALE;
    int g = (idx / NSCALE) % NG;
    int b = idx / (NSCALE * NG);
    int p = threadIdx.x;                  // 0..1023
    float cam;
    if (s == 0) {
        const float* pp = ws + WS_P2 + (size_t)(b * NG + g) * NPAD + 1 + p;
        float t = 0.f;
#pragma unroll
        for (int c = 0; c < IC; ++c) t += pp[(size_t)c * PSTRIDE_O];
        cam = t;
    } else {
        cam = ws[WS_VS + ((size_t)(s * BB + b) * NG + g) * NPAD + 1 + p];
    }
    redA[p] = cam;
    redB[p] = cam;
    __syncthreads();
    for (int st = 512; st > 0; st >>= 1) {
        if (p < st) {
            redA[p] = fminf(redA[p], redA[p + st]);
            redB[p] = fmaxf(redB[p], redB[p + st]);
        }
        __syncthreads();
    }
    float mn = redA[0], mx = redB[0];
    float camn = (cam - mn) / (mx - mn + 1e-6f);
    out[(size_t)idx * PP + p] = camn;
    float bin = camn >= CAMTHR ? 1.0f : 0.0f;
    __syncthreads();
    img[p] = bin;
    __syncthreads();
    int y = p >> 5, x = p & 31;
    float m = 0.f;
    for (int dx = -KPAD; dx <= KPAD; ++dx) {
        int xx = x + dx;
        if (xx >= 0 && xx < 32) m = fmaxf(m, img[(y << 5) | xx]);
    }
    tmp[p] = m;
    __syncthreads();
    m = 0.f;
    for (int dy = -KPAD; dy <= KPAD; ++dy) {
        int yy = y + dy;
        if (yy >= 0 && yy < 32) m = fmaxf(m, tmp[(yy << 5) | x]);
    }
    __syncthreads();
    img[p] = m;                           // dilated
    __syncthreads();
    float e;
    if (x < KPAD || x > 31 - KPAD) {
        e = 0.f;
    } else {
        e = 1e30f;
        for (int dx = -KPAD; dx <= KPAD; ++dx) e = fminf(e, img[(y << 5) | (x + dx)]);
    }
    tmp[p] = e;
    __syncthreads();
    float ev;
    if (y < KPAD || y > 31 - KPAD) {
        ev = 0.f;
    } else {
        ev = 1e30f;
        for (int dy = -KPAD; dy <= KPAD; ++dy) ev = fminf(ev, tmp[((y + dy) << 5) | x]);
    }
    out[(size_t)(BB * NG * NSCALE) * PP + (size_t)idx * PP + p] = ev;
    bool fg = ev > 0.5f;
    redA[p] = fg ? (float)x : 1e9f;
    redB[p] = fg ? (float)x : -1e9f;
    __syncthreads();
    for (int st = 512; st > 0; st >>= 1) {
        if (p < st) {
            redA[p] = fminf(redA[p], redA[p + st]);
            redB[p] = fmaxf(redB[p], redB[p + st]);
        }
        __syncthreads();
    }
    float xmin = redA[0], xmax = redB[0];
    __syncthreads();
    redA[p] = fg ? (float)y : 1e9f;
    redB[p] = fg ? (float)y : -1e9f;
    __syncthreads();
    for (int st = 512; st > 0; st >>= 1) {
        if (p < st) {
            redA[p] = fminf(redA[p], redA[p + st]);
            redB[p] = fmaxf(redB[p], redB[p + st]);
        }
        __syncthreads();
    }
    if (p == 0) {
        float ymin = redA[0], ymax = redB[0];
        float* bb = out + (size_t)(BB * NG * NSCALE) * PP * 2 + (size_t)idx * 4;
        if (xmax < -1e8f) {
            bb[0] = 0.f; bb[1] = 0.f; bb[2] = 1.f; bb[3] = 1.f;
        } else {
            bb[0] = xmin; bb[1] = ymin; bb[2] = xmax; bb[3] = ymax;
        }
    }
}

extern "C" void kernel_launch(void* const* d_in, const int* in_sizes, int n_in,
                              void* d_out, int out_size, void* d_ws, size_t ws_size,
                              hipStream_t stream) {
    const float* A = (const float*)d_in[0];
    const int* pos = (const int*)d_in[1];
    float* out = (float*)d_out;
    float* ws = (float*)d_ws;

    const float* rs2 = ws + WS_ROWSUM + 2 * BB * NPAD;   // block 10
    const float* rs1 = ws + WS_ROWSUM + 1 * BB * NPAD;   // block 9
    const float* rs0 = ws + WS_ROWSUM + 0 * BB * NPAD;   // block 8
    float* VS3 = ws + WS_VS + 3 * BB * NG * NPAD;
    float* VS2 = ws + WS_VS + 2 * BB * NG * NPAD;
    float* VS1 = ws + WS_VS + 1 * BB * NG * NPAD;

    prep_kernel<<<(N_ROWSUM + N_INITV + 3) / 4, 256, 0, stream>>>(A, pos, ws);
    // S10: V3 -> P0 (transposed)
    stage_kernel<<<IC * BB, STG_THREADS, 0, stream>>>(A, rs2, VS3, nullptr,
                                                      ws + WS_P0, nullptr, 10, 1);
    // S9: one-time reduce(P0) -> V2 ; multiply -> P1 (transposed)
    stage_kernel<<<IC * BB, STG_THREADS, 0, stream>>>(A, rs1, nullptr, ws + WS_P0,
                                                      ws + WS_P1, VS2, 9, 1);
    // S8: one-time reduce(P1) -> V1 ; multiply -> P2 (old layout)
    stage_kernel<<<IC * BB, STG_THREADS, 0, stream>>>(A, rs0, nullptr, ws + WS_P1,
                                                      ws + WS_P2, VS1, 8, 0);
    post_kernel<<<BB * NG * NSCALE, 1024, 0, stream>>>(ws, out);
}